// Round 5
// baseline (17.292 us; speedup 1.0000x reference)
//
#include <hip/hip_runtime.h>

typedef float fvec4 __attribute__((ext_vector_type(4)));
typedef float fvec2 __attribute__((ext_vector_type(2)));

// out[b,n,e] = x*W[0,e] + y*W[1,e] + d*W[2,e] + bias[e]
// d = |x - x_depot| + |y - y_depot|, depot = node 0 of batch b.
//
// 256 threads/block, 64 rows/block (8 rows/iter x 8 iters), grid = 2000.
// lane_e = tid&31 (fvec4 slot in EMBED=128), rgrp = tid>>5.
// This round: PLAIN stores (A/B vs round-4's nontemporal), constexpr N
// (static magic-div), loads inside the loop (lower register pressure,
// compiler software-pipelines them).
__global__ __launch_bounds__(256) void slap_init_embed_kernel(
    const float* __restrict__ locs,   // [B, N, 2]
    const float* __restrict__ W,      // [3, 128]
    const float* __restrict__ bias,   // [128]
    float* __restrict__ out)          // [B, N, 128]
{
    constexpr int N = 2000;
    constexpr int ROWS_PER_ITER = 8;
    constexpr int ITERS = 8;

    const int tid    = threadIdx.x;
    const int lane_e = tid & 31;
    const int rgrp   = tid >> 5;
    const int block_base = blockIdx.x * (ROWS_PER_ITER * ITERS);   // first row

    // 2 KB of weights: L1-broadcast
    const fvec4* __restrict__ W4 = (const fvec4*)W;
    const fvec4 w0 = W4[lane_e];
    const fvec4 w1 = W4[32 + lane_e];
    const fvec4 w2 = W4[64 + lane_e];
    const fvec4 bb = ((const fvec4*)bias)[lane_e];

    fvec4* __restrict__ out4 = (fvec4*)out + blockIdx.x * 2048 + tid;

#pragma unroll
    for (int i = 0; i < ITERS; ++i) {
        const int row = block_base + i * ROWS_PER_ITER + rgrp;
        const int b = row / N;                       // static magic-mul
        const fvec2 xy  = ((const fvec2*)locs)[row];
        const fvec2 xy0 = ((const fvec2*)locs)[b * N];
        const float x = xy.x, y = xy.y;
        const float d = fabsf(x - xy0.x) + fabsf(y - xy0.y);
        fvec4 o;
        o.x = fmaf(x, w0.x, fmaf(y, w1.x, fmaf(d, w2.x, bb.x)));
        o.y = fmaf(x, w0.y, fmaf(y, w1.y, fmaf(d, w2.y, bb.y)));
        o.z = fmaf(x, w0.z, fmaf(y, w1.z, fmaf(d, w2.z, bb.z)));
        o.w = fmaf(x, w0.w, fmaf(y, w1.w, fmaf(d, w2.w, bb.w)));
        out4[i * 256] = o;                            // plain store
    }
}

extern "C" void kernel_launch(void* const* d_in, const int* in_sizes, int n_in,
                              void* d_out, int out_size, void* d_ws, size_t ws_size,
                              hipStream_t stream) {
    const float* locs = (const float*)d_in[0];  // [B,N,2]
    const float* W    = (const float*)d_in[1];  // [3,128]
    const float* bias = (const float*)d_in[2];  // [128]
    float* out = (float*)d_out;

    const int B = 64, N = 2000;
    const int total_rows = B * N;                        // 128000
    const int rows_per_block = 64;                       // 8 per iter x 8 iters
    const int blocks = (total_rows + rows_per_block - 1) / rows_per_block; // 2000
    slap_init_embed_kernel<<<blocks, 256, 0, stream>>>(locs, W, bias, out);
}

// Round 6
// 16.821 us; speedup vs baseline: 1.0280x; 1.0280x over previous
//
#include <hip/hip_runtime.h>

typedef float fvec4 __attribute__((ext_vector_type(4)));
typedef float fvec2 __attribute__((ext_vector_type(2)));

// out[b,n,e] = x*W[0,e] + y*W[1,e] + d*W[2,e] + bias[e]
// d = |x - x_depot| + |y - y_depot|, depot = node 0 of batch b.
//
// Best measured variant (R4, 16.79 us): 256 threads/block, 64 rows/block
// (8 rows/iter x 8 iters), grid = 2000 -> 31 waves/CU, one residency round.
// lane_e = tid&31 (fvec4 slot in EMBED=128), rgrp = tid>>5.
// Nontemporal 16 B stores; output is write-once, never re-read by us.
__global__ __launch_bounds__(256) void slap_init_embed_kernel(
    const float* __restrict__ locs,   // [B, N, 2]
    const float* __restrict__ W,      // [3, 128]
    const float* __restrict__ bias,   // [128]
    float* __restrict__ out,          // [B, N, 128]
    int N)
{
    constexpr int ROWS_PER_ITER = 8;
    constexpr int ITERS = 8;

    const int tid    = threadIdx.x;
    const int lane_e = tid & 31;
    const int rgrp   = tid >> 5;
    const int block_base = blockIdx.x * (ROWS_PER_ITER * ITERS);   // first row

    // 2 KB of weights: L1-broadcast, loaded once per thread for 8 rows
    const fvec4* __restrict__ W4 = (const fvec4*)W;
    const fvec4 w0 = W4[lane_e];
    const fvec4 w1 = W4[32 + lane_e];
    const fvec4 w2 = W4[64 + lane_e];
    const fvec4 bb = ((const fvec4*)bias)[lane_e];

    // prefetch per-row scalars for all iterations (independent loads)
    fvec2 xy[ITERS], xy0[ITERS];
#pragma unroll
    for (int i = 0; i < ITERS; ++i) {
        const int row = block_base + i * ROWS_PER_ITER + rgrp;
        const int b = row / N;
        xy[i]  = ((const fvec2*)locs)[row];
        xy0[i] = ((const fvec2*)locs)[b * N];
    }

    fvec4* __restrict__ out4 = (fvec4*)out + blockIdx.x * 2048 + tid;
#pragma unroll
    for (int i = 0; i < ITERS; ++i) {
        const float x = xy[i].x, y = xy[i].y;
        const float d = fabsf(x - xy0[i].x) + fabsf(y - xy0[i].y);
        fvec4 o;
        o.x = fmaf(x, w0.x, fmaf(y, w1.x, fmaf(d, w2.x, bb.x)));
        o.y = fmaf(x, w0.y, fmaf(y, w1.y, fmaf(d, w2.y, bb.y)));
        o.z = fmaf(x, w0.z, fmaf(y, w1.z, fmaf(d, w2.z, bb.z)));
        o.w = fmaf(x, w0.w, fmaf(y, w1.w, fmaf(d, w2.w, bb.w)));
        __builtin_nontemporal_store(o, out4 + i * 256);
    }
}

extern "C" void kernel_launch(void* const* d_in, const int* in_sizes, int n_in,
                              void* d_out, int out_size, void* d_ws, size_t ws_size,
                              hipStream_t stream) {
    const float* locs = (const float*)d_in[0];  // [B,N,2]
    const float* W    = (const float*)d_in[1];  // [3,128]
    const float* bias = (const float*)d_in[2];  // [128]
    float* out = (float*)d_out;

    const int B = 64;
    const int N = 2000;

    const int total_rows = B * N;                        // 128000
    const int rows_per_block = 64;                       // 8 per iter x 8 iters
    const int blocks = (total_rows + rows_per_block - 1) / rows_per_block; // 2000
    slap_init_embed_kernel<<<blocks, 256, 0, stream>>>(locs, W, bias, out, N);
}